// Round 1
// baseline (707.796 us; speedup 1.0000x reference)
//
#include <hip/hip_runtime.h>
#include <math.h>

// Problem constants
// x: [B=64][N=2048][I=16] fp32, W: [N=2048][O=32][I=16][D=32] fp32
// out: [B=64][O=32][D=32] fp32
#define B_ 64
#define N_ 2048
#define O_ 32
#define I_ 16
#define D_ 32
#define NB 16        // batch elements per block (b-group size)
#define NBG 4        // number of b-groups = B_/NB
#define DQ 16        // threads along d; each thread owns 2 d's
#define BLK 512      // 32 o * 16 dq

// Fused pass kernel: recompute u_hat[b,n,o,:] in registers, optional
// softmax(u_hat . v) routing weights, accumulate s partials over an n-chunk.
// UNIFORM=1: c = 1/32 (first iteration, b=0), v unused.
template <int UNIFORM>
__global__ __launch_bounds__(BLK) void caps_pass(
    const float* __restrict__ x, const float* __restrict__ W,
    const float* __restrict__ v, float* __restrict__ partial, int NC) {
  const int t  = threadIdx.x;
  const int o  = t >> 4;        // 0..31
  const int dq = t & 15;        // 0..15
  const int d0 = dq * 2;        // thread owns d0, d0+1
  const int ch = blockIdx.x;    // n-chunk
  const int bg = blockIdx.y;    // b-group 0..3

  __shared__ float ls_logit[NB][O_];
  __shared__ float ls_c[NB][O_];

  float2 vreg[NB];
  if (!UNIFORM) {
#pragma unroll
    for (int bb = 0; bb < NB; ++bb) {
      int b = bg * NB + bb;
      vreg[bb] = *(const float2*)&v[((b * O_ + o) * D_) + d0];
    }
  }

  float2 sacc[NB];
#pragma unroll
  for (int bb = 0; bb < NB; ++bb) sacc[bb] = make_float2(0.f, 0.f);

  const int n0 = ch * NC;
  for (int nl = 0; nl < NC; ++nl) {
    const int n = n0 + nl;

    // ---- phase 1: u_hat fragments (2 d's per thread, 16 b's) ----
    float2 w[I_];
    const float* Wb = W + ((size_t)n * O_ + o) * (I_ * D_) + d0;
#pragma unroll
    for (int i = 0; i < I_; ++i) w[i] = *(const float2*)(Wb + i * D_);

    float2 u[NB];
    const float* xb = x + ((size_t)(bg * NB) * N_ + n) * I_;
#pragma unroll
    for (int bb = 0; bb < NB; ++bb) {
      const float* xp = xb + (size_t)bb * N_ * I_;  // wave-uniform -> s_load
      float ax = 0.f, ay = 0.f;
#pragma unroll
      for (int i = 0; i < I_; ++i) {
        float xv = xp[i];
        ax = fmaf(xv, w[i].x, ax);
        ay = fmaf(xv, w[i].y, ay);
      }
      u[bb] = make_float2(ax, ay);
    }

    if (UNIFORM) {
#pragma unroll
      for (int bb = 0; bb < NB; ++bb) {
        sacc[bb].x += u[bb].x;
        sacc[bb].y += u[bb].y;
      }
    } else {
      // ---- phase 2: logits = u_hat . v, reduce over d (16 dq lanes) ----
      float lp[NB];
#pragma unroll
      for (int bb = 0; bb < NB; ++bb)
        lp[bb] = u[bb].x * vreg[bb].x + u[bb].y * vreg[bb].y;
#pragma unroll
      for (int m = 1; m < 16; m <<= 1) {
#pragma unroll
        for (int bb = 0; bb < NB; ++bb) lp[bb] += __shfl_xor(lp[bb], m, 16);
      }
      if (dq == 0) {
#pragma unroll
        for (int bb = 0; bb < NB; ++bb) ls_logit[bb][o] = lp[bb];
      }
      __syncthreads();
      // softmax over o: remap t -> (sb, so), 32-lane row reductions
      {
        int sb = t >> 5, so = t & 31;
        float l = ls_logit[sb][so];
        float mx = l;
#pragma unroll
        for (int m = 16; m >= 1; m >>= 1) mx = fmaxf(mx, __shfl_xor(mx, m, 32));
        float e = __expf(l - mx);
        float ssum = e;
#pragma unroll
        for (int m = 16; m >= 1; m >>= 1) ssum += __shfl_xor(ssum, m, 32);
        ls_c[sb][so] = e / ssum;
      }
      __syncthreads();
      // ---- phase 3: s += c * u_hat ----
#pragma unroll
      for (int bb = 0; bb < NB; ++bb) {
        float cc = ls_c[bb][o];
        sacc[bb].x = fmaf(cc, u[bb].x, sacc[bb].x);
        sacc[bb].y = fmaf(cc, u[bb].y, sacc[bb].y);
      }
    }
  }

  const float scale = UNIFORM ? (1.f / 32.f) : 1.f;
#pragma unroll
  for (int bb = 0; bb < NB; ++bb) {
    int b = bg * NB + bb;
    float2 val = make_float2(sacc[bb].x * scale, sacc[bb].y * scale);
    *(float2*)&partial[(((size_t)ch * B_ + b) * O_ + o) * D_ + d0] = val;
  }
}

// Sum partials over chunks, then squash along d (32 lanes per (b,o) row).
// out[g] = (prev ? prev[g] : 0) + squash(s)[g]
__global__ __launch_bounds__(256) void reduce_squash(
    const float* __restrict__ part, int chunks,
    const float* __restrict__ prev, float* __restrict__ out) {
  int g = blockIdx.x * 256 + threadIdx.x;  // b*1024 + o*32 + d, 65536 total
  float s = 0.f;
  for (int ch = 0; ch < chunks; ++ch) s += part[(size_t)ch * 65536 + g];
  float sq = s * s;
#pragma unroll
  for (int m = 16; m >= 1; m >>= 1) sq += __shfl_xor(sq, m, 32);
  float scale = sq / ((1.f + sq) * (sqrtf(sq) + 1e-6f));
  float r = s * scale;
  if (prev) r += prev[g];
  out[g] = r;
}

extern "C" void kernel_launch(void* const* d_in, const int* in_sizes, int n_in,
                              void* d_out, int out_size, void* d_ws,
                              size_t ws_size, hipStream_t stream) {
  const float* x = (const float*)d_in[0];
  const float* W = (const float*)d_in[1];  // leading dim of 1 dropped
  float* out = (float*)d_out;

  float* v1 = (float*)d_ws;            // 65536 floats
  float* vsum = v1 + 65536;            // 65536 floats
  float* partial = vsum + 65536;       // chunks * 65536 floats

  int chunks = 128;
  while (chunks > 1 &&
         (size_t)(131072 + (size_t)chunks * 65536) * 4 > ws_size)
    chunks >>= 1;
  int NC = N_ / chunks;

  dim3 grid(chunks, NBG);

  // iter 1: b=0 -> c uniform -> s1 -> v1
  caps_pass<1><<<grid, BLK, 0, stream>>>(x, W, nullptr, partial, NC);
  reduce_squash<<<256, 256, 0, stream>>>(partial, chunks, nullptr, v1);
  // iter 2: logits = u.v1 -> s2 -> vsum = v1 + squash(s2)
  caps_pass<0><<<grid, BLK, 0, stream>>>(x, W, v1, partial, NC);
  reduce_squash<<<256, 256, 0, stream>>>(partial, chunks, v1, vsum);
  // iter 3: logits = u.(v1+v2) -> s3 -> out = squash(s3)
  caps_pass<0><<<grid, BLK, 0, stream>>>(x, W, vsum, partial, NC);
  reduce_squash<<<256, 256, 0, stream>>>(partial, chunks, nullptr, out);
}

// Round 2
// 563.143 us; speedup vs baseline: 1.2569x; 1.2569x over previous
//
#include <hip/hip_runtime.h>
#include <math.h>

#define B_ 64
#define N_ 2048
#define O_ 32
#define I_ 16
#define D_ 32
#define OD_ 1024
#define BLK 512

typedef __attribute__((ext_vector_type(8))) short bf16x8;
typedef __attribute__((ext_vector_type(4))) float f32x4;

union FragU { unsigned u[4]; bf16x8 f; };

// Dekker split: f = hi + lo, hi = truncate-to-bf16 (bits in HIGH half of h),
// lo = bf16(f - hi) (bits in LOW half of l). (hi+lo) recovers fp32-level
// accuracy (~2^-17 rel) through bf16 MFMA.
__device__ __forceinline__ void dk_split(float f, unsigned &h, unsigned &l) {
  unsigned u = __float_as_uint(f);
  h = u & 0xffff0000u;
  float lo = f - __uint_as_float(h);
  l = __float_as_uint(lo) >> 16;
}

// Fused routing pass. Per n: u_hat tile via 2x mfma_16x16x32_bf16 (split-K
// packing: A=[xh|xl], B1=[wh|wh], B2=[wl|wl] -> exact (xh+xl)(wh+wl)).
// UNIFORM=1: c=1/32, accumulate s directly in MFMA accumulators. Else:
// logits = u.v (16-lane shfl reduce), softmax over o in LDS, s += c*u.
// Wave = col-group cg (128 od-cols = 4 o's). Block = 8 waves = 1024 cols x
// 16 b's. C-layout: row=q*4+r, col=lane&15. A-layout: m=lane&15, k=q*8+j.
template <int UNIFORM>
__global__ __launch_bounds__(BLK, 4) void mfma_pass(
    const float* __restrict__ x, const float* __restrict__ W,
    const float* __restrict__ v, float* __restrict__ partial, int NC) {
  const int tid = threadIdx.x;
  const int lane = tid & 63;
  const int cg = tid >> 6;      // wave id = col-group 0..7
  const int q = lane >> 4;      // quad 0..3
  const int c = lane & 15;
  const int ch = blockIdx.x;    // n-chunk
  const int bg = blockIdx.y;    // b-group 0..3 (16 b's)

  __shared__ float ls_logit[16 * O_];
  __shared__ float ls_c[16 * O_];

  f32x4 s_t[8];
#pragma unroll
  for (int ct = 0; ct < 8; ++ct) s_t[ct] = (f32x4){0.f, 0.f, 0.f, 0.f};

  const int n0 = ch * NC;
  const int ih = (q & 1) * 8;  // i-offset loaded by this lane
  const float* xrow = x + ((size_t)(bg * 16 + c) * N_) * I_ + ih;

  for (int nl = 0; nl < NC; ++nl) {
    const int n = n0 + nl;

    // ---- A fragment: x[b = bg*16 + c, n, i] ----
    const float* xp = xrow + (size_t)n * I_;
    float4 xv0 = *(const float4*)xp;
    float4 xv1 = *(const float4*)(xp + 4);
    float xv[8] = {xv0.x, xv0.y, xv0.z, xv0.w, xv1.x, xv1.y, xv1.z, xv1.w};
    FragU a1;
#pragma unroll
    for (int p = 0; p < 4; ++p) {
      unsigned h0, l0, h1, l1;
      dk_split(xv[2 * p], h0, l0);
      dk_split(xv[2 * p + 1], h1, l1);
      // quads 0,1 hold xh (k=0..15); quads 2,3 hold xl (k=16..31)
      a1.u[p] = (q < 2) ? ((h0 >> 16) | h1) : (l0 | (l1 << 16));
    }

    f32x4 u_t[8];
    // ---- B fragments + MFMA per 16-col tile ----
#pragma unroll
    for (int ct = 0; ct < 8; ++ct) {
      const int o = cg * 4 + (ct >> 1);
      const int d = (ct & 1) * 16 + c;
      const float* wp = W + (((size_t)n * O_ + o) * I_ + ih) * D_ + d;
      FragU b1, b2;
#pragma unroll
      for (int p = 0; p < 4; ++p) {
        unsigned h0, l0, h1, l1;
        dk_split(wp[(2 * p) * D_], h0, l0);
        dk_split(wp[(2 * p + 1) * D_], h1, l1);
        b1.u[p] = (h0 >> 16) | h1;   // wh (i = k&15 duplicates across K-halves)
        b2.u[p] = l0 | (l1 << 16);   // wl
      }
      if (UNIFORM) {
        s_t[ct] = __builtin_amdgcn_mfma_f32_16x16x32_bf16(a1.f, b1.f, s_t[ct], 0, 0, 0);
        s_t[ct] = __builtin_amdgcn_mfma_f32_16x16x32_bf16(a1.f, b2.f, s_t[ct], 0, 0, 0);
      } else {
        f32x4 acc = (f32x4){0.f, 0.f, 0.f, 0.f};
        acc = __builtin_amdgcn_mfma_f32_16x16x32_bf16(a1.f, b1.f, acc, 0, 0, 0);
        u_t[ct] = __builtin_amdgcn_mfma_f32_16x16x32_bf16(a1.f, b2.f, acc, 0, 0, 0);
      }
    }

    if (!UNIFORM) {
      // ---- logits: logit[b, o] = sum_d u[b,o,d] * v[b,o,d] ----
#pragma unroll
      for (int ol = 0; ol < 4; ++ol) {
        float lg[4] = {0.f, 0.f, 0.f, 0.f};
#pragma unroll
        for (int hf = 0; hf < 2; ++hf) {
          int ct = ol * 2 + hf;
          int odc = cg * 128 + ct * 16 + c;
#pragma unroll
          for (int r = 0; r < 4; ++r)
            lg[r] = fmaf(u_t[ct][r], v[(size_t)(bg * 16 + q * 4 + r) * OD_ + odc], lg[r]);
        }
#pragma unroll
        for (int r = 0; r < 4; ++r) {
#pragma unroll
          for (int m = 1; m < 16; m <<= 1) lg[r] += __shfl_xor(lg[r], m);
        }
        if (c == 0) {
#pragma unroll
          for (int r = 0; r < 4; ++r)
            ls_logit[(q * 4 + r) * O_ + cg * 4 + ol] = lg[r];
        }
      }
      __syncthreads();
      // ---- softmax over o: 512 threads = 16 b x 32 o ----
      {
        int b_l = tid >> 5, o = tid & 31;
        float l = ls_logit[b_l * O_ + o];
        float mx = l;
#pragma unroll
        for (int m = 16; m >= 1; m >>= 1) mx = fmaxf(mx, __shfl_xor(mx, m));
        float e = __expf(l - mx);
        float sm = e;
#pragma unroll
        for (int m = 16; m >= 1; m >>= 1) sm += __shfl_xor(sm, m);
        ls_c[b_l * O_ + o] = e / sm;
      }
      __syncthreads();
      // ---- s += c * u ----
#pragma unroll
      for (int ol = 0; ol < 4; ++ol) {
        int o = cg * 4 + ol;
        float cc[4];
#pragma unroll
        for (int r = 0; r < 4; ++r) cc[r] = ls_c[(q * 4 + r) * O_ + o];
#pragma unroll
        for (int hf = 0; hf < 2; ++hf) {
          int ct = ol * 2 + hf;
#pragma unroll
          for (int r = 0; r < 4; ++r)
            s_t[ct][r] = fmaf(cc[r], u_t[ct][r], s_t[ct][r]);
        }
      }
    }
  }

  const float scale = UNIFORM ? (1.f / 32.f) : 1.f;
#pragma unroll
  for (int ct = 0; ct < 8; ++ct) {
#pragma unroll
    for (int r = 0; r < 4; ++r) {
      partial[((size_t)ch * B_ + bg * 16 + q * 4 + r) * OD_ + cg * 128 + ct * 16 + c] =
          s_t[ct][r] * scale;
    }
  }
}

// Sum partials over chunks, then squash along d (32 lanes per (b,o) row).
// out[g] = (prev ? prev[g] : 0) + squash(s)[g]
__global__ __launch_bounds__(256) void reduce_squash(
    const float* __restrict__ part, int chunks,
    const float* __restrict__ prev, float* __restrict__ out) {
  int g = blockIdx.x * 256 + threadIdx.x;  // b*1024 + o*32 + d, 65536 total
  float s = 0.f;
  for (int ch = 0; ch < chunks; ++ch) s += part[(size_t)ch * 65536 + g];
  float sq = s * s;
#pragma unroll
  for (int m = 16; m >= 1; m >>= 1) sq += __shfl_xor(sq, m, 32);
  float scale = sq / ((1.f + sq) * (sqrtf(sq) + 1e-6f));
  float r = s * scale;
  if (prev) r += prev[g];
  out[g] = r;
}

extern "C" void kernel_launch(void* const* d_in, const int* in_sizes, int n_in,
                              void* d_out, int out_size, void* d_ws,
                              size_t ws_size, hipStream_t stream) {
  const float* x = (const float*)d_in[0];
  const float* W = (const float*)d_in[1];  // leading dim of 1 dropped
  float* out = (float*)d_out;

  float* v1 = (float*)d_ws;       // 65536 floats
  float* vsum = v1 + 65536;       // 65536 floats
  float* partial = vsum + 65536;  // chunks * 65536 floats

  int chunks = 128;  // confirmed fits ws (round-1 WRITE_SIZE == 32 MB)
  while (chunks > 1 &&
         (size_t)(131072 + (size_t)chunks * 65536) * 4 > ws_size)
    chunks >>= 1;
  int NC = N_ / chunks;

  dim3 grid(chunks, 4);

  // iter 1: c uniform -> s1 -> v1
  mfma_pass<1><<<grid, BLK, 0, stream>>>(x, W, nullptr, partial, NC);
  reduce_squash<<<256, 256, 0, stream>>>(partial, chunks, nullptr, v1);
  // iter 2: logits = u.v1 -> s2 -> vsum = v1 + squash(s2)
  mfma_pass<0><<<grid, BLK, 0, stream>>>(x, W, v1, partial, NC);
  reduce_squash<<<256, 256, 0, stream>>>(partial, chunks, v1, vsum);
  // iter 3: logits = u.(v1+v2) -> s3 -> out = squash(s3)
  mfma_pass<0><<<grid, BLK, 0, stream>>>(x, W, vsum, partial, NC);
  reduce_squash<<<256, 256, 0, stream>>>(partial, chunks, nullptr, out);
}

// Round 3
// 526.627 us; speedup vs baseline: 1.3440x; 1.0693x over previous
//
#include <hip/hip_runtime.h>
#include <math.h>

#define B_ 64
#define N_ 2048
#define O_ 32
#define I_ 16
#define D_ 32
#define OD_ 1024
#define BLK 512

typedef __attribute__((ext_vector_type(8))) short bf16x8;
typedef __attribute__((ext_vector_type(4))) float f32x4;

union FragU { unsigned u[4]; uint4 v; bf16x8 f; };

// Dekker split to bf16 halves: f = hi + lo exactly representable products
// through bf16 MFMA: (xh+xl)(wh+wl).
__device__ __forceinline__ void dk_split(float f, unsigned &h, unsigned &l) {
  unsigned u = __float_as_uint(f);
  h = u & 0xffff0000u;
  float lo = f - __uint_as_float(h);
  l = __float_as_uint(lo) >> 16;
}

__device__ __forceinline__ void dk_split16(float f, unsigned short &h,
                                           unsigned short &l) {
  unsigned u = __float_as_uint(f);
  unsigned hu = u & 0xffff0000u;
  h = (unsigned short)(u >> 16);
  float lo = f - __uint_as_float(hu);
  l = (unsigned short)(__float_as_uint(lo) >> 16);
}

__device__ __forceinline__ unsigned pk(unsigned short e0, unsigned short e1) {
  return (unsigned)e0 | ((unsigned)e1 << 16);
}

// ---- prep: W[n][o][i][d] fp32 -> WP packed B-fragments ----
// WP u4 idx = (((n*32+o)*2 + dhalf)*4 + sel*2 + qp)*16 + c
// lane dword p packs i = qp*8+2p (lo16), qp*8+2p+1 (hi16); sel0=hi, sel1=lo.
__global__ __launch_bounds__(256) void prep_w(const float* __restrict__ W,
                                              uint4* __restrict__ WP) {
  int t = blockIdx.x * 256 + threadIdx.x;  // 2,097,152 = n*o*d
  int d = t & 31, o = (t >> 5) & 31, n = t >> 10;
  const float* wp = W + ((size_t)(n * O_ + o) * I_) * D_ + d;
  unsigned short hh[I_], ll[I_];
#pragma unroll
  for (int i = 0; i < I_; ++i) dk_split16(wp[i * D_], hh[i], ll[i]);
  int c = d & 15, dhalf = d >> 4;
  size_t base = ((size_t)(n * O_ + o) * 2 + dhalf) * 4;
#pragma unroll
  for (int sel = 0; sel < 2; ++sel) {
    const unsigned short* e = sel ? ll : hh;
#pragma unroll
    for (int qp = 0; qp < 2; ++qp) {
      uint4 u;
      u.x = pk(e[qp * 8 + 0], e[qp * 8 + 1]);
      u.y = pk(e[qp * 8 + 2], e[qp * 8 + 3]);
      u.z = pk(e[qp * 8 + 4], e[qp * 8 + 5]);
      u.w = pk(e[qp * 8 + 6], e[qp * 8 + 7]);
      WP[(base + sel * 2 + qp) * 16 + c] = u;
    }
  }
}

// ---- prep: x[b][n][i] fp32 -> XP packed A-fragments ----
// XP u4 idx = (((bg*2048+n)*2 + sel)*2 + qp)*16 + c ; b = bg*16 + c
__global__ __launch_bounds__(256) void prep_x(const float* __restrict__ x,
                                              uint4* __restrict__ XP) {
  int t = blockIdx.x * 256 + threadIdx.x;  // 131,072 = bg*n*c
  int c = t & 15, n = (t >> 4) & 2047, bg = t >> 15;
  const float* xp = x + ((size_t)(bg * 16 + c) * N_ + n) * I_;
  unsigned short hh[I_], ll[I_];
#pragma unroll
  for (int i = 0; i < I_; ++i) dk_split16(xp[i], hh[i], ll[i]);
  size_t base = ((size_t)bg * N_ + n) * 4;
#pragma unroll
  for (int sel = 0; sel < 2; ++sel) {
    const unsigned short* e = sel ? ll : hh;
#pragma unroll
    for (int qp = 0; qp < 2; ++qp) {
      uint4 u;
      u.x = pk(e[qp * 8 + 0], e[qp * 8 + 1]);
      u.y = pk(e[qp * 8 + 2], e[qp * 8 + 3]);
      u.z = pk(e[qp * 8 + 4], e[qp * 8 + 5]);
      u.w = pk(e[qp * 8 + 6], e[qp * 8 + 7]);
      XP[(base + sel * 2 + qp) * 16 + c] = u;
    }
  }
}

// ---- fused routing pass, pre-packed fragments ----
// Per n: u_hat tile = mfma(A_hi, B) + mfma(A_lo, B), B=[wh|wl].
// Wave cg covers o = cg*4..cg*4+3 (8 16-col tiles). 16 b per block (bg).
template <int UNIFORM>
__global__ __launch_bounds__(BLK, 4) void mfma_pass2(
    const uint4* __restrict__ XP, const uint4* __restrict__ WP,
    const float* __restrict__ v, float* __restrict__ partial, int NC) {
  const int tid = threadIdx.x;
  const int lane = tid & 63;
  const int cg = tid >> 6;
  const int q = lane >> 4;
  const int c = lane & 15;
  const int qp = q & 1;
  const int ch = blockIdx.x;
  const int bg = blockIdx.y;
  const int bq = (q >> 1) * 32 + qp * 16 + c;  // B lane offset within 64-u4 tile

  __shared__ float ls_logit[16 * O_];
  __shared__ float ls_c[16 * O_];

  f32x4 s_t[8];
#pragma unroll
  for (int ct = 0; ct < 8; ++ct) s_t[ct] = (f32x4){0.f, 0.f, 0.f, 0.f};

  const int n0 = ch * NC;
  for (int nl = 0; nl < NC; ++nl) {
    const int n = n0 + nl;

    const uint4* xb = XP + (((size_t)bg * N_ + n) * 4 + qp) * 16 + c;
    FragU ahi, alo;
    ahi.v = xb[0];    // sel 0
    alo.v = xb[32];   // sel 1

    const uint4* wb = WP + (size_t)n * 4096 + cg * 8 * 64 + bq;
    FragU bfr[8];
#pragma unroll
    for (int ct = 0; ct < 8; ++ct) bfr[ct].v = wb[ct * 64];

    f32x4 u_t[8];
#pragma unroll
    for (int ct = 0; ct < 8; ++ct) {
      if (UNIFORM) {
        s_t[ct] = __builtin_amdgcn_mfma_f32_16x16x32_bf16(ahi.f, bfr[ct].f, s_t[ct], 0, 0, 0);
        s_t[ct] = __builtin_amdgcn_mfma_f32_16x16x32_bf16(alo.f, bfr[ct].f, s_t[ct], 0, 0, 0);
      } else {
        f32x4 acc = (f32x4){0.f, 0.f, 0.f, 0.f};
        acc = __builtin_amdgcn_mfma_f32_16x16x32_bf16(ahi.f, bfr[ct].f, acc, 0, 0, 0);
        u_t[ct] = __builtin_amdgcn_mfma_f32_16x16x32_bf16(alo.f, bfr[ct].f, acc, 0, 0, 0);
      }
    }

    if (!UNIFORM) {
      // logits: logit[b,o] = sum_d u[b,o,d]*v[b,o,d]; C-layout row=q*4+r, col=c
#pragma unroll
      for (int ol = 0; ol < 4; ++ol) {
        float lg[4] = {0.f, 0.f, 0.f, 0.f};
#pragma unroll
        for (int hf = 0; hf < 2; ++hf) {
          int ct = ol * 2 + hf;
          int odc = cg * 128 + ct * 16 + c;
#pragma unroll
          for (int r = 0; r < 4; ++r)
            lg[r] = fmaf(u_t[ct][r], v[(size_t)(bg * 16 + q * 4 + r) * OD_ + odc], lg[r]);
        }
#pragma unroll
        for (int r = 0; r < 4; ++r) {
#pragma unroll
          for (int m = 1; m < 16; m <<= 1) lg[r] += __shfl_xor(lg[r], m);
        }
        if (c == 0) {
#pragma unroll
          for (int r = 0; r < 4; ++r)
            ls_logit[(q * 4 + r) * O_ + cg * 4 + ol] = lg[r];
        }
      }
      __syncthreads();
      // softmax over o: 512 threads = 16 b x 32 o
      {
        int b_l = tid >> 5, o = tid & 31;
        float l = ls_logit[b_l * O_ + o];
        float mx = l;
#pragma unroll
        for (int m = 16; m >= 1; m >>= 1) mx = fmaxf(mx, __shfl_xor(mx, m));
        float e = __expf(l - mx);
        float sm = e;
#pragma unroll
        for (int m = 16; m >= 1; m >>= 1) sm += __shfl_xor(sm, m);
        ls_c[b_l * O_ + o] = e / sm;
      }
      __syncthreads();
      // s += c * u
#pragma unroll
      for (int ol = 0; ol < 4; ++ol) {
        int o = cg * 4 + ol;
        float cc[4];
#pragma unroll
        for (int r = 0; r < 4; ++r) cc[r] = ls_c[(q * 4 + r) * O_ + o];
#pragma unroll
        for (int hf = 0; hf < 2; ++hf) {
          int ct = ol * 2 + hf;
#pragma unroll
          for (int r = 0; r < 4; ++r)
            s_t[ct][r] = fmaf(cc[r], u_t[ct][r], s_t[ct][r]);
        }
      }
    }
  }

  const float scale = UNIFORM ? (1.f / 32.f) : 1.f;
#pragma unroll
  for (int ct = 0; ct < 8; ++ct) {
#pragma unroll
    for (int r = 0; r < 4; ++r) {
      partial[((size_t)ch * B_ + bg * 16 + q * 4 + r) * OD_ + cg * 128 + ct * 16 + c] =
          s_t[ct][r] * scale;
    }
  }
}

// ---- fallback (round-2 path, used only if ws too small for WP/XP) ----
template <int UNIFORM>
__global__ __launch_bounds__(BLK, 4) void mfma_pass_fb(
    const float* __restrict__ x, const float* __restrict__ W,
    const float* __restrict__ v, float* __restrict__ partial, int NC) {
  const int tid = threadIdx.x;
  const int lane = tid & 63;
  const int cg = tid >> 6;
  const int q = lane >> 4;
  const int c = lane & 15;
  const int ch = blockIdx.x;
  const int bg = blockIdx.y;

  __shared__ float ls_logit[16 * O_];
  __shared__ float ls_c[16 * O_];

  f32x4 s_t[8];
#pragma unroll
  for (int ct = 0; ct < 8; ++ct) s_t[ct] = (f32x4){0.f, 0.f, 0.f, 0.f};

  const int n0 = ch * NC;
  const int ih = (q & 1) * 8;
  const float* xrow = x + ((size_t)(bg * 16 + c) * N_) * I_ + ih;

  for (int nl = 0; nl < NC; ++nl) {
    const int n = n0 + nl;
    const float* xp = xrow + (size_t)n * I_;
    float4 xv0 = *(const float4*)xp;
    float4 xv1 = *(const float4*)(xp + 4);
    float xv[8] = {xv0.x, xv0.y, xv0.z, xv0.w, xv1.x, xv1.y, xv1.z, xv1.w};
    FragU a1;
#pragma unroll
    for (int p = 0; p < 4; ++p) {
      unsigned h0, l0, h1, l1;
      dk_split(xv[2 * p], h0, l0);
      dk_split(xv[2 * p + 1], h1, l1);
      a1.u[p] = (q < 2) ? ((h0 >> 16) | h1) : (l0 | (l1 << 16));
    }
    f32x4 u_t[8];
#pragma unroll
    for (int ct = 0; ct < 8; ++ct) {
      const int o = cg * 4 + (ct >> 1);
      const int d = (ct & 1) * 16 + c;
      const float* wp = W + (((size_t)n * O_ + o) * I_ + ih) * D_ + d;
      FragU b1, b2;
#pragma unroll
      for (int p = 0; p < 4; ++p) {
        unsigned h0, l0, h1, l1;
        dk_split(wp[(2 * p) * D_], h0, l0);
        dk_split(wp[(2 * p + 1) * D_], h1, l1);
        b1.u[p] = (h0 >> 16) | h1;
        b2.u[p] = l0 | (l1 << 16);
      }
      if (UNIFORM) {
        s_t[ct] = __builtin_amdgcn_mfma_f32_16x16x32_bf16(a1.f, b1.f, s_t[ct], 0, 0, 0);
        s_t[ct] = __builtin_amdgcn_mfma_f32_16x16x32_bf16(a1.f, b2.f, s_t[ct], 0, 0, 0);
      } else {
        f32x4 acc = (f32x4){0.f, 0.f, 0.f, 0.f};
        acc = __builtin_amdgcn_mfma_f32_16x16x32_bf16(a1.f, b1.f, acc, 0, 0, 0);
        u_t[ct] = __builtin_amdgcn_mfma_f32_16x16x32_bf16(a1.f, b2.f, acc, 0, 0, 0);
      }
    }
    if (!UNIFORM) {
#pragma unroll
      for (int ol = 0; ol < 4; ++ol) {
        float lg[4] = {0.f, 0.f, 0.f, 0.f};
#pragma unroll
        for (int hf = 0; hf < 2; ++hf) {
          int ct = ol * 2 + hf;
          int odc = cg * 128 + ct * 16 + c;
#pragma unroll
          for (int r = 0; r < 4; ++r)
            lg[r] = fmaf(u_t[ct][r], v[(size_t)(bg * 16 + q * 4 + r) * OD_ + odc], lg[r]);
        }
#pragma unroll
        for (int r = 0; r < 4; ++r) {
#pragma unroll
          for (int m = 1; m < 16; m <<= 1) lg[r] += __shfl_xor(lg[r], m);
        }
        if (c == 0) {
#pragma unroll
          for (int r = 0; r < 4; ++r)
            ls_logit[(q * 4 + r) * O_ + cg * 4 + ol] = lg[r];
        }
      }
      __syncthreads();
      {
        int b_l = tid >> 5, o = tid & 31;
        float l = ls_logit[b_l * O_ + o];
        float mx = l;
#pragma unroll
        for (int m = 16; m >= 1; m >>= 1) mx = fmaxf(mx, __shfl_xor(mx, m));
        float e = __expf(l - mx);
        float sm = e;
#pragma unroll
        for (int m = 16; m >= 1; m >>= 1) sm += __shfl_xor(sm, m);
        ls_c[b_l * O_ + o] = e / sm;
      }
      __syncthreads();
#pragma unroll
      for (int ol = 0; ol < 4; ++ol) {
        int o = cg * 4 + ol;
        float cc[4];
#pragma unroll
        for (int r = 0; r < 4; ++r) cc[r] = ls_c[(q * 4 + r) * O_ + o];
#pragma unroll
        for (int hf = 0; hf < 2; ++hf) {
          int ct = ol * 2 + hf;
#pragma unroll
          for (int r = 0; r < 4; ++r)
            s_t[ct][r] = fmaf(cc[r], u_t[ct][r], s_t[ct][r]);
        }
      }
    }
  }

  const float scale = UNIFORM ? (1.f / 32.f) : 1.f;
#pragma unroll
  for (int ct = 0; ct < 8; ++ct) {
#pragma unroll
    for (int r = 0; r < 4; ++r) {
      partial[((size_t)ch * B_ + bg * 16 + q * 4 + r) * OD_ + cg * 128 + ct * 16 + c] =
          s_t[ct][r] * scale;
    }
  }
}

// Sum partials over chunks, squash along d; out = (prev?:0) + squash(s)
__global__ __launch_bounds__(256) void reduce_squash(
    const float* __restrict__ part, int chunks,
    const float* __restrict__ prev, float* __restrict__ out) {
  int g = blockIdx.x * 256 + threadIdx.x;
  float s = 0.f;
  for (int ch = 0; ch < chunks; ++ch) s += part[(size_t)ch * 65536 + g];
  float sq = s * s;
#pragma unroll
  for (int m = 16; m >= 1; m >>= 1) sq += __shfl_xor(sq, m, 32);
  float scale = sq / ((1.f + sq) * (sqrtf(sq) + 1e-6f));
  float r = s * scale;
  if (prev) r += prev[g];
  out[g] = r;
}

extern "C" void kernel_launch(void* const* d_in, const int* in_sizes, int n_in,
                              void* d_out, int out_size, void* d_ws,
                              size_t ws_size, hipStream_t stream) {
  const float* x = (const float*)d_in[0];
  const float* W = (const float*)d_in[1];
  float* out = (float*)d_out;

  const size_t XP_FLOATS = 4ull * 2048 * 4 * 16 * 4;        // 2,097,152
  const size_t WP_FLOATS = 2048ull * 32 * 2 * 4 * 16 * 4;   // 33,554,432

  float* v1 = (float*)d_ws;
  float* vsum = v1 + 65536;
  float* partial = vsum + 65536;

  // choose chunks for the new path
  int chunks = 128;
  while (chunks > 8 &&
         (131072 + (size_t)chunks * 65536 + XP_FLOATS + WP_FLOATS) * 4 > ws_size)
    chunks >>= 1;
  bool packed_path =
      (131072 + (size_t)chunks * 65536 + XP_FLOATS + WP_FLOATS) * 4 <= ws_size;

  if (packed_path) {
    uint4* XP = (uint4*)(partial + (size_t)chunks * 65536);
    uint4* WP = XP + XP_FLOATS / 4;
    int NC = N_ / chunks;
    dim3 grid(chunks, 4);

    prep_x<<<512, 256, 0, stream>>>(x, XP);
    prep_w<<<8192, 256, 0, stream>>>(W, WP);

    mfma_pass2<1><<<grid, BLK, 0, stream>>>(XP, WP, nullptr, partial, NC);
    reduce_squash<<<256, 256, 0, stream>>>(partial, chunks, nullptr, v1);
    mfma_pass2<0><<<grid, BLK, 0, stream>>>(XP, WP, v1, partial, NC);
    reduce_squash<<<256, 256, 0, stream>>>(partial, chunks, v1, vsum);
    mfma_pass2<0><<<grid, BLK, 0, stream>>>(XP, WP, vsum, partial, NC);
    reduce_squash<<<256, 256, 0, stream>>>(partial, chunks, nullptr, out);
  } else {
    chunks = 128;
    while (chunks > 1 && (131072 + (size_t)chunks * 65536) * 4 > ws_size)
      chunks >>= 1;
    int NC = N_ / chunks;
    dim3 grid(chunks, 4);

    mfma_pass_fb<1><<<grid, BLK, 0, stream>>>(x, W, nullptr, partial, NC);
    reduce_squash<<<256, 256, 0, stream>>>(partial, chunks, nullptr, v1);
    mfma_pass_fb<0><<<grid, BLK, 0, stream>>>(x, W, v1, partial, NC);
    reduce_squash<<<256, 256, 0, stream>>>(partial, chunks, v1, vsum);
    mfma_pass_fb<0><<<grid, BLK, 0, stream>>>(x, W, vsum, partial, NC);
    reduce_squash<<<256, 256, 0, stream>>>(partial, chunks, nullptr, out);
  }
}